// Round 5
// baseline (225.802 us; speedup 1.0000x reference)
//
#include <hip/hip_runtime.h>
#include <math.h>

// Problem shape (fixed by the reference): x is [B=8, S=4096, D=1024] fp32.
constexpr int B = 8;
constexpr int S = 4096;
constexpr int D = 1024;
constexpr int DQ = D / 4;            // float4 groups per row = 256
constexpr int PLANE4 = S * DQ;       // 2^20 float4 per [S,D] plane
constexpr int TOTAL4 = B * PLANE4;   // 2^23 float4 total

constexpr int THREADS = 256;
constexpr int BLOCKS  = 2048;        // 256 CU x 8 blocks/CU = one resident cohort
constexpr int NTHREAD = THREADS * BLOCKS;   // 2^19 threads
constexpr int ITERS   = TOTAL4 / NTHREAD;   // 16 float4 per thread, over time

// Native Clang vector type for nontemporal builtins (HIP float4 is rejected).
typedef float floatx4 __attribute__((ext_vector_type(4)));

// -log2(10000) / D
#define NEG_L2_10000_OVER_D (-13.287712379549449f / 1024.0f)

// Lessons so far: 1 float4 of live state per thread wins (R1: 8/thread +14us,
// R3: 4/thread +8us — register-space amortization loses occupancy/TLP);
// nt load+store is weak-positive (R4: -2.4us). This round amortizes compute
// across TIME instead of registers: grid-stride with stride = 2^19 float4
// makes (idx4 & 255) loop-invariant, so d0 and the four exp2f wave factors
// hoist out of the loop entirely. Per iteration: nt load -> decode s ->
// 4 mul + 2 sin + 2 cos + 4 add -> nt store. Trans ops halve (8 -> 4 per
// float4). 2048 blocks = exactly one resident cohort (no dispatch churn,
// no tail); each of the 16 sweeps covers a contiguous 8 MiB frontier.
// fs * exp2f((d0+j)*c) is the exact expression form validated in R3 =>
// bitwise-identical output (absmax stays 0.03125).
__global__ __launch_bounds__(256)
void pe_add_kernel(const float* __restrict__ x, float* __restrict__ out) {
    const int t0 = blockIdx.x * THREADS + threadIdx.x;   // 0 .. 2^19-1

    const floatx4* __restrict__ xv = (const floatx4*)x;
    floatx4*       __restrict__ ov = (floatx4*)out;

    const int d0 = (t0 & (DQ - 1)) << 2;   // invariant: stride keeps low 8 bits

    const float w0 = exp2f((float)(d0 + 0) * NEG_L2_10000_OVER_D);
    const float w1 = exp2f((float)(d0 + 1) * NEG_L2_10000_OVER_D);
    const float w2 = exp2f((float)(d0 + 2) * NEG_L2_10000_OVER_D);
    const float w3 = exp2f((float)(d0 + 3) * NEG_L2_10000_OVER_D);

#pragma unroll 4
    for (int i = 0; i < ITERS; ++i) {
        const int idx4 = t0 + i * NTHREAD;
        floatx4 v = __builtin_nontemporal_load(&xv[idx4]);

        const int s = (idx4 & (PLANE4 - 1)) >> 8;   // row within the plane
        const float fs = (float)s;

        v.x += __sinf(fs * w0);   // even dim -> sin
        v.y += __cosf(fs * w1);   // odd  dim -> cos
        v.z += __sinf(fs * w2);
        v.w += __cosf(fs * w3);

        __builtin_nontemporal_store(v, &ov[idx4]);
    }
}

extern "C" void kernel_launch(void* const* d_in, const int* in_sizes, int n_in,
                              void* d_out, int out_size, void* d_ws, size_t ws_size,
                              hipStream_t stream) {
    const float* x = (const float*)d_in[0];
    float* out = (float*)d_out;

    pe_add_kernel<<<BLOCKS, THREADS, 0, stream>>>(x, out);
}

// Round 6
// 224.461 us; speedup vs baseline: 1.0060x; 1.0060x over previous
//
#include <hip/hip_runtime.h>
#include <math.h>

// Problem shape (fixed by the reference): x is [B=8, S=4096, D=1024] fp32.
constexpr int B = 8;
constexpr int S = 4096;
constexpr int D = 1024;
constexpr int DQ = D / 4;            // float4 groups per row = 256
constexpr int DQ_SHIFT = 8;          // log2(DQ)
constexpr int PLANE4 = S * DQ;       // 2^20 float4 per [S,D] plane
constexpr int TOTAL4 = B * PLANE4;   // 2^23 float4 total
constexpr size_t PE_BYTES = (size_t)PLANE4 * 16;   // 16.8 MB pe table

// Native Clang vector type for nontemporal builtins (HIP float4 is rejected).
typedef float floatx4 __attribute__((ext_vector_type(4)));

// -log2(10000) / D
#define NEG_L2_10000_OVER_D (-13.287712379549449f / 1024.0f)

// ---------------------------------------------------------------------------
// Issue-cycle model (R0..R5 evidence): the fused kernel spends ~124 SIMD
// issue-cycles per wave per float4 (30 VALU x 2cy + 8 quarter-rate trans x
// 8cy) against an ~800cy memory budget with 8 resident waves -> 8x124 ~ 1000
// > 800: the SIMD issue port, not HBM, is the binding resource (matches the
// measured ~57us vs ~43us stream floor, ratio 1.33). R3/R5 tried to cut
// compute but broke the memory structure (register amortization / persistent
// stride) and lost. This version cuts compute while keeping R4's proven
// structure EXACTLY: two kernels.
//   1) pe_build: PE value depends only on (s,d) -> build the [S,DQ] float4
//      table (16.8 MB) in workspace. Token-identical expressions to the
//      validated kernel.
//   2) pe_add: R4's shape (1 float4/thread, 32768 blocks, nt x/out) but the
//      per-thread work collapses to: nt-load x, cacheable load pe, 4 adds,
//      nt-store (~16 issue-cy/wave, 8x under budget -> memory-bound).
//      pe is re-read per batch plane; L3 (256 MiB) keeps it resident after
//      the first pass, so extra HBM is only ~34 MB round-trip.
// IEEE addition is commutative bitwise -> output identical to the fused
// version (absmax stays 0.03125).
// ---------------------------------------------------------------------------

__global__ __launch_bounds__(256)
void pe_build_kernel(float* __restrict__ pe) {
    const int pidx = blockIdx.x * blockDim.x + threadIdx.x;  // 0 .. PLANE4-1
    const int dq = pidx & (DQ - 1);
    const int s  = pidx >> DQ_SHIFT;
    const int d0 = dq << 2;

    const float fs = (float)s;
    const float a0 = fs * exp2f((float)(d0 + 0) * NEG_L2_10000_OVER_D);
    const float a1 = fs * exp2f((float)(d0 + 1) * NEG_L2_10000_OVER_D);
    const float a2 = fs * exp2f((float)(d0 + 2) * NEG_L2_10000_OVER_D);
    const float a3 = fs * exp2f((float)(d0 + 3) * NEG_L2_10000_OVER_D);

    floatx4 p;
    p.x = __sinf(a0);   // even dim -> sin
    p.y = __cosf(a1);   // odd  dim -> cos
    p.z = __sinf(a2);
    p.w = __cosf(a3);

    ((floatx4*)pe)[pidx] = p;   // plain store: let it land in L2/L3
}

__global__ __launch_bounds__(256)
void pe_add_kernel(const float* __restrict__ x, const float* __restrict__ pe,
                   float* __restrict__ out) {
    const int idx4 = blockIdx.x * blockDim.x + threadIdx.x;  // 0 .. TOTAL4-1

    const floatx4* __restrict__ xv = (const floatx4*)x;
    const floatx4* __restrict__ pv = (const floatx4*)pe;
    floatx4*       __restrict__ ov = (floatx4*)out;

    const floatx4 v = __builtin_nontemporal_load(&xv[idx4]);  // zero-reuse
    const floatx4 p = pv[idx4 & (PLANE4 - 1)];                // cacheable, 8x reuse

    floatx4 r = v;
    r.x += p.x;
    r.y += p.y;
    r.z += p.z;
    r.w += p.w;

    __builtin_nontemporal_store(r, &ov[idx4]);
}

// Fallback (R4 fused kernel) in case the workspace is too small for the table.
__global__ __launch_bounds__(256)
void pe_add_fused_kernel(const float* __restrict__ x, float* __restrict__ out) {
    const int idx4 = blockIdx.x * blockDim.x + threadIdx.x;

    const floatx4* __restrict__ xv = (const floatx4*)x;
    floatx4*       __restrict__ ov = (floatx4*)out;

    floatx4 v = __builtin_nontemporal_load(&xv[idx4]);

    const int pidx = idx4 & (PLANE4 - 1);
    const int dq   = pidx & (DQ - 1);
    const int s    = pidx >> DQ_SHIFT;
    const int d0   = dq << 2;

    const float fs = (float)s;
    const float a0 = fs * exp2f((float)(d0 + 0) * NEG_L2_10000_OVER_D);
    const float a1 = fs * exp2f((float)(d0 + 1) * NEG_L2_10000_OVER_D);
    const float a2 = fs * exp2f((float)(d0 + 2) * NEG_L2_10000_OVER_D);
    const float a3 = fs * exp2f((float)(d0 + 3) * NEG_L2_10000_OVER_D);

    v.x += __sinf(a0);
    v.y += __cosf(a1);
    v.z += __sinf(a2);
    v.w += __cosf(a3);

    __builtin_nontemporal_store(v, &ov[idx4]);
}

extern "C" void kernel_launch(void* const* d_in, const int* in_sizes, int n_in,
                              void* d_out, int out_size, void* d_ws, size_t ws_size,
                              hipStream_t stream) {
    const float* x = (const float*)d_in[0];
    float* out = (float*)d_out;
    const int threads = 256;

    if (d_ws != nullptr && ws_size >= PE_BYTES) {
        float* pe = (float*)d_ws;
        pe_build_kernel<<<PLANE4 / threads, threads, 0, stream>>>(pe);
        pe_add_kernel<<<TOTAL4 / threads, threads, 0, stream>>>(x, pe, out);
    } else {
        pe_add_fused_kernel<<<TOTAL4 / threads, threads, 0, stream>>>(x, out);
    }
}

// Round 7
// 217.004 us; speedup vs baseline: 1.0405x; 1.0344x over previous
//
#include <hip/hip_runtime.h>
#include <math.h>

// Problem shape (fixed by the reference): x is [B=8, S=4096, D=1024] fp32.
constexpr int B = 8;
constexpr int S = 4096;
constexpr int D = 1024;
constexpr int DQ = D / 4;            // float4 groups per row = 256
constexpr int DQ_SHIFT = 8;          // log2(DQ)
constexpr int PLANE4 = S * DQ;       // 2^20 float4 per [S,D] plane
constexpr int TOTAL4 = B * PLANE4;   // 2^23 float4 total

// Native Clang vector type: __builtin_nontemporal_load/store accept this
// (HIP's float4 struct is rejected). Lowers to global_load/store_dwordx4 nt.
typedef float floatx4 __attribute__((ext_vector_type(4)));

// -log2(10000) / D
#define NEG_L2_10000_OVER_D (-13.287712379549449f / 1024.0f)

// FINAL (R4 structure, session-best 217.1us). Evidence trail:
//  - R1 (8-plane batch reuse): 233.8us — multi-float4 live state kills TLP.
//  - R3 (4-row contiguous chunks): 227.3us — same, even with perfect locality.
//  - R5 (persistent grid-stride): 225.8us — loop/addr state beats the savings.
//  - R6 (precomputed PE table, compute removed entirely): 224.5us — proves
//    the transcendental work is fully hidden under the memory stream; this
//    kernel is memory-bound at the achievable mixed read+write rate.
//  - nt load/store: -2.4us vs plain (R0 219.5 -> R4 217.1); zero-reuse
//    stream, skip cache allocation.
// 1 float4 per thread, ~20 VGPR -> 8 waves/SIMD, maximal TLP; monolithic
// 32768-block dispatch; compute is per-thread independent and hidden.
__global__ __launch_bounds__(256)
void pe_add_kernel(const float* __restrict__ x, float* __restrict__ out) {
    const int idx4 = blockIdx.x * blockDim.x + threadIdx.x;  // 0 .. TOTAL4-1

    const floatx4* __restrict__ xv = (const floatx4*)x;
    floatx4*       __restrict__ ov = (floatx4*)out;

    // Issue the load first so its latency overlaps the pe computation.
    floatx4 v = __builtin_nontemporal_load(&xv[idx4]);

    const int pidx = idx4 & (PLANE4 - 1);   // position within the [S,D] plane
    const int dq   = pidx & (DQ - 1);
    const int s    = pidx >> DQ_SHIFT;
    const int d0   = dq << 2;

    const float fs = (float)s;
    const float a0 = fs * exp2f((float)(d0 + 0) * NEG_L2_10000_OVER_D);
    const float a1 = fs * exp2f((float)(d0 + 1) * NEG_L2_10000_OVER_D);
    const float a2 = fs * exp2f((float)(d0 + 2) * NEG_L2_10000_OVER_D);
    const float a3 = fs * exp2f((float)(d0 + 3) * NEG_L2_10000_OVER_D);

    v.x += __sinf(a0);   // even dim -> sin
    v.y += __cosf(a1);   // odd  dim -> cos
    v.z += __sinf(a2);
    v.w += __cosf(a3);

    __builtin_nontemporal_store(v, &ov[idx4]);
}

extern "C" void kernel_launch(void* const* d_in, const int* in_sizes, int n_in,
                              void* d_out, int out_size, void* d_ws, size_t ws_size,
                              hipStream_t stream) {
    const float* x = (const float*)d_in[0];
    float* out = (float*)d_out;

    const int threads = 256;
    const int blocks = TOTAL4 / threads;   // 32768
    pe_add_kernel<<<blocks, threads, 0, stream>>>(x, out);
}